// Round 4
// baseline (130.618 us; speedup 1.0000x reference)
//
#include <hip/hip_runtime.h>

#define TT 200
#define NN 512
#define DD 4
#define HH 64
#define LL 32
#define SB 16                // sequences per block (fills MFMA M=16)
#define BPB (NN / SB)        // 32 blocks per batch
#define KP 72                // ushort pitch per h row (144B: 16B-aligned rows)

typedef short bf16x8 __attribute__((ext_vector_type(8)));
typedef float f32x4 __attribute__((ext_vector_type(4)));

union U8 { unsigned short s[8]; bf16x8 v; };

__device__ __forceinline__ float sigmoidf_(float x) {
    float e = __expf(-x);
    return __builtin_amdgcn_rcpf(1.0f + e);
}
__device__ __forceinline__ float tanhf_(float x) {
    float xc = fminf(fmaxf(x, -15.0f), 15.0f);
    float e = __expf(-2.0f * xc);
    return (1.0f - e) * __builtin_amdgcn_rcpf(1.0f + e);
}

// f32 -> (hi, lo) bf16 limbs by truncation: x = hi + lo + err, |err| <= 2^-16 |x|
__device__ __forceinline__ void split2(float x, unsigned short& hi, unsigned short& lo) {
    unsigned u = __float_as_uint(x);
    hi = (unsigned short)(u >> 16);
    float lf = x - __uint_as_float(u & 0xffff0000u);
    lo = (unsigned short)(__float_as_uint(lf) >> 16);
}

__global__ __launch_bounds__(256, 1)
void gru_traj_kernel(const float* __restrict__ xg,    // (B,T,N,D)
                     const float* __restrict__ W_ih,  // (192,4)
                     const float* __restrict__ W_hh,  // (192,64)
                     const float* __restrict__ b_ih,  // (192,)
                     const float* __restrict__ b_hh,  // (192,)
                     const float* __restrict__ W_enc, // (32,64)
                     const float* __restrict__ b_enc, // (32,)
                     float* __restrict__ out)         // (B,N,32)
{
    __shared__ __align__(16) float xall[TT][SB][DD];         // 51.2 KB: whole x trajectory
    __shared__ __align__(16) unsigned short hhi[2][SB][KP];  // h hi-limbs, double buffered
    __shared__ __align__(16) unsigned short hlo[2][SB][KP];  // h lo-limbs
    __shared__ __align__(16) float hsf[SB][HH + 4];          // f32 h for epilogue

    const int tid = threadIdx.x;
    const int bid = blockIdx.x;
    const int b   = bid >> 5;                // bid / BPB
    const int n0  = (bid & (BPB - 1)) * SB;

    const int w  = tid >> 6;     // wave -> gate tiles {w, w+4, w+8}: r,z,n for units 16w..16w+15
    const int l  = tid & 63;
    const int lr = l & 15;       // A-row / B-col / C-col within tile
    const int lg = l >> 4;       // k-group (A/B), row-group (C)

    // ---- preload entire x trajectory for this block into LDS (only global reads) ----
    // per t: 16 seqs x 4 d = 64 contiguous floats = 16 float4
    {
        float4* dst = reinterpret_cast<float4*>(&xall[0][0][0]);
        for (int f = tid; f < TT * 16; f += 256) {
            const int t = f >> 4, q = f & 15;
            dst[f] = *reinterpret_cast<const float4*>(
                xg + ((size_t)(b * TT + t) * NN + n0) * DD + q * 4);
        }
    }

    // ---- B fragments: W_hh^T tiles as bf16 hi/lo limbs (resident all 200 steps) ----
    bf16x8 bh[3][2], bl[3][2];
    #pragma unroll
    for (int i = 0; i < 3; ++i) {
        const int g = i * 64 + 16 * w + lr;
        #pragma unroll
        for (int kc = 0; kc < 2; ++kc) {
            const float* p = W_hh + g * HH + kc * 32 + lg * 8;
            U8 uh, ul;
            #pragma unroll
            for (int j = 0; j < 8; ++j) split2(p[j], uh.s[j], ul.s[j]);
            bh[i][kc] = uh.v; bl[i][kc] = ul.v;
        }
    }
    // per-lane gate constants (unit u = 16w + lr)
    float wih[3][4], bih[3], bhh[3];
    #pragma unroll
    for (int i = 0; i < 3; ++i) {
        const int g = i * 64 + 16 * w + lr;
        wih[i][0] = W_ih[g * DD + 0]; wih[i][1] = W_ih[g * DD + 1];
        wih[i][2] = W_ih[g * DD + 2]; wih[i][3] = W_ih[g * DD + 3];
        bih[i] = b_ih[g]; bhh[i] = b_hh[g];
    }

    // ---- init: zero limb buffers (h0 = 0) ----
    for (int idx = tid; idx < 2 * SB * KP / 2; idx += 256) {
        reinterpret_cast<unsigned*>(hhi)[idx] = 0u;
        reinterpret_cast<unsigned*>(hlo)[idx] = 0u;
    }
    float hreg[4] = {0.f, 0.f, 0.f, 0.f};   // h[s = lg*4+r][u = 16w+lr]
    __syncthreads();

    for (int t = 0; t < TT; ++t) {
        const int cur = t & 1, nxt = cur ^ 1;

        // ---- A fragments: direct bf16-limb LDS loads ----
        bf16x8 ah[2], al[2];
        #pragma unroll
        for (int kc = 0; kc < 2; ++kc) {
            ah[kc] = *reinterpret_cast<const bf16x8*>(&hhi[cur][lr][kc * 32 + lg * 8]);
            al[kc] = *reinterpret_cast<const bf16x8*>(&hlo[cur][lr][kc * 32 + lg * 8]);
        }

        // ---- gx from LDS-resident x (independent of MFMA chain) ----
        float gxv[3][4];
        #pragma unroll
        for (int r = 0; r < 4; ++r) {
            const int s = lg * 4 + r;
            float4 x4 = *reinterpret_cast<const float4*>(&xall[t][s][0]);
            #pragma unroll
            for (int i = 0; i < 3; ++i)
                gxv[i][r] = fmaf(wih[i][0], x4.x, fmaf(wih[i][1], x4.y,
                            fmaf(wih[i][2], x4.z, fmaf(wih[i][3], x4.w, bih[i]))));
        }

        // ---- gh = h @ W_hh^T via split-bf16 MFMA; two short accumulator chains ----
        f32x4 accA[3], accB[3];
        #pragma unroll
        for (int i = 0; i < 3; ++i) {
            accA[i][0] = bhh[i]; accA[i][1] = bhh[i]; accA[i][2] = bhh[i]; accA[i][3] = bhh[i];
            accB[i][0] = 0.f;    accB[i][1] = 0.f;    accB[i][2] = 0.f;    accB[i][3] = 0.f;
        }
        #pragma unroll
        for (int i = 0; i < 3; ++i) {
            accA[i] = __builtin_amdgcn_mfma_f32_16x16x32_bf16(ah[0], bh[i][0], accA[i], 0, 0, 0);
            accA[i] = __builtin_amdgcn_mfma_f32_16x16x32_bf16(ah[1], bh[i][1], accA[i], 0, 0, 0);
            accB[i] = __builtin_amdgcn_mfma_f32_16x16x32_bf16(al[0], bh[i][0], accB[i], 0, 0, 0);
            accB[i] = __builtin_amdgcn_mfma_f32_16x16x32_bf16(al[1], bh[i][1], accB[i], 0, 0, 0);
            accB[i] = __builtin_amdgcn_mfma_f32_16x16x32_bf16(ah[0], bl[i][0], accB[i], 0, 0, 0);
            accB[i] = __builtin_amdgcn_mfma_f32_16x16x32_bf16(ah[1], bl[i][1], accB[i], 0, 0, 0);
        }

        // ---- gates + h update (in-register), split at writer, store to buf[nxt] ----
        #pragma unroll
        for (int r = 0; r < 4; ++r) {
            const int s = lg * 4 + r;
            const int u = 16 * w + lr;
            float rg = sigmoidf_((accA[0][r] + accB[0][r]) + gxv[0][r]);
            float z  = sigmoidf_((accA[1][r] + accB[1][r]) + gxv[1][r]);
            float ghn = accA[2][r] + accB[2][r];
            float nn = tanhf_(fmaf(rg, ghn, gxv[2][r]));
            float hn = fmaf(z, hreg[r] - nn, nn);    // (1-z)n + z h
            hreg[r] = hn;
            unsigned short hi, lo;
            split2(hn, hi, lo);
            hhi[nxt][s][u] = hi;
            hlo[nxt][s][u] = lo;
        }
        __syncthreads();   // h_{t+1} limbs visible; buf[cur] free next iteration
    }

    // ---- epilogue: out = h @ W_enc^T + b_enc ----
    #pragma unroll
    for (int r = 0; r < 4; ++r)
        hsf[lg * 4 + r][16 * w + lr] = hreg[r];
    __syncthreads();
    for (int o = tid; o < SB * LL; o += 256) {
        const int s = o >> 5, li = o & 31;
        float a = b_enc[li];
        #pragma unroll
        for (int k = 0; k < HH; ++k)
            a = fmaf(hsf[s][k], W_enc[li * HH + k], a);
        out[(bid * SB + s) * LL + li] = a;
    }
}

extern "C" void kernel_launch(void* const* d_in, const int* in_sizes, int n_in,
                              void* d_out, int out_size, void* d_ws, size_t ws_size,
                              hipStream_t stream) {
    const float* xg    = (const float*)d_in[0];
    const float* W_ih  = (const float*)d_in[1];
    const float* W_hh  = (const float*)d_in[2];
    const float* b_ih  = (const float*)d_in[3];
    const float* b_hh  = (const float*)d_in[4];
    const float* W_enc = (const float*)d_in[5];
    const float* b_enc = (const float*)d_in[6];
    float* out = (float*)d_out;

    dim3 grid(8 * BPB), block(256);   // 256 blocks -> exactly 1 block/CU
    hipLaunchKernelGGL(gru_traj_kernel, grid, block, 0, stream,
                       xg, W_ih, W_hh, b_ih, b_hh, W_enc, b_enc, out);
}